// Round 9
// baseline (670.127 us; speedup 1.0000x reference)
//
#include <hip/hip_runtime.h>

// out[b,c,y,x] = sum_{kdy,kdx in [0,9)} corr[b, kdy*9+kdx, y+4-kdy, x+4-kdx] * feat[b,c, y+4-kdy, x+4-kdx]
// (zero padding outside [0,96) in both spatial dims)

#define RR 4
#define DD 9
#define D2 81
#define Bn 16
#define Cn 256
#define Hn 96
#define Wn 96
#define HWn (Hn*Wn)

#define NTX 12            // x-lane groups
#define TXR 8             // x outputs per thread
#define NTC 32            // channel lanes
#define CT  2             // channels per thread
#define NCB (NTC*CT)      // 64 channels per block
#define NCG (Cn/NCB)      // 4 channel groups
#define NTH (NTX*NTC)     // 384 threads
#define LW  100           // padded LDS row width: cols 0..3 zero pad, 4..99 data; 81*100*4 = 32400 B
#define LW4 (LW/4)        // 25 float4 per row

__global__ __launch_bounds__(NTH, 2)
void corrT9_kernel(const float* __restrict__ corr,
                   const float* __restrict__ feat,
                   float* __restrict__ out)
{
    __shared__ float lds[D2 * LW];          // 32400 B

    // XCD-chunked bijective swizzle (grid 6144 % 8 == 0)
    int bid = blockIdx.x;
    int sw  = (bid & 7) * (gridDim.x >> 3) + (bid >> 3);
    int cg  = sw & (NCG - 1);               // channel-group fastest: corr L2 reuse
    int y   = (sw >> 2) % Hn;
    int b   = sw / (NCG * Hn);

    const int tid = threadIdx.x;
    const float* corrb = corr + (size_t)b * D2 * HWn;

    // ---- stage corr rows into LDS, x-shifted by kdx, zero-padded ----
    // lds[row][col] = corr[b, row, y+4-kdy, col - kdx]  (0 if OOB), row = kdy*9+kdx
    for (int idx = tid; idx < D2 * LW4; idx += NTH) {
        int row = idx / LW4;
        int c4  = idx - row * LW4;
        int kdy = row / DD;
        int kdx = row - kdy * DD;
        int sy  = y + RR - kdy;
        float4 v = make_float4(0.f, 0.f, 0.f, 0.f);
        if (sy >= 0 && sy < Hn) {
            const float* src = corrb + (size_t)row * HWn + sy * Wn;
            int col0 = c4 * 4;
            #pragma unroll
            for (int e = 0; e < 4; ++e) {
                int sx = col0 + e - kdx;
                if (sx >= 0 && sx < Wn) (&v.x)[e] = src[sx];
            }
        }
        *reinterpret_cast<float4*>(&lds[row * LW + c4 * 4]) = v;
    }
    __syncthreads();

    const int tx = tid % NTX;
    const int tc = tid / NTX;
    const int x0 = tx * TXR;
    const int c0 = cg * NCB + tc * CT;

    const float* featb = feat + ((size_t)b * Cn + c0) * HWn;
    const float4 z4 = make_float4(0.f, 0.f, 0.f, 0.f);

    float acc[CT][TXR] = {};

    // contiguous valid kdy range: sy = y+4-kdy in [0,96)
    const int klo = max(0, y - (Hn - 1 - RR));
    const int khi = min(DD - 1, y + RR);

// unpack one feat source row (syv) into static array F (R3/R8-proven SROA shape)
#define LOADF_K(F, syv)                                                                   \
    {                                                                                     \
        const float* frow = featb + (syv) * Wn + x0 - RR;                                 \
        _Pragma("unroll")                                                                 \
        for (int c = 0; c < CT; ++c) {                                                    \
            const float* p = frow + (size_t)c * HWn;                                      \
            float4 f0 = (tx == 0)       ? z4 : *reinterpret_cast<const float4*>(p);       \
            float4 f1 = *reinterpret_cast<const float4*>(p + 4);                          \
            float4 f2 = *reinterpret_cast<const float4*>(p + 8);                          \
            float4 f3 = (tx == NTX - 1) ? z4 : *reinterpret_cast<const float4*>(p + 12);  \
            F[c][0]=f0.x;  F[c][1]=f0.y;  F[c][2]=f0.z;  F[c][3]=f0.w;                    \
            F[c][4]=f1.x;  F[c][5]=f1.y;  F[c][6]=f1.z;  F[c][7]=f1.w;                    \
            F[c][8]=f2.x;  F[c][9]=f2.y;  F[c][10]=f2.z; F[c][11]=f2.w;                   \
            F[c][12]=f3.x; F[c][13]=f3.y; F[c][14]=f3.z; F[c][15]=f3.w;                   \
        }                                                                                 \
    }

// consume one kdy from F: 18 LDS b128 (depth-1 prefetched) + 144 FMA
#define COMPUTE_K(F, kdyv)                                                                \
    {                                                                                     \
        const float4* base = reinterpret_cast<const float4*>(lds) + (tx * 2 + 1)          \
                             + (kdyv) * DD * LW4;                                         \
        float4 ca = base[0];                                                              \
        float4 cb = base[1];                                                              \
        _Pragma("unroll")                                                                 \
        for (int kdx = 0; kdx < DD; ++kdx) {                                              \
            float4 na = ca, nb = cb;                                                      \
            if (kdx < DD - 1) {                                                           \
                na = base[(kdx + 1) * LW4];                                               \
                nb = base[(kdx + 1) * LW4 + 1];                                           \
            }                                                                             \
            float cv[8] = {ca.x, ca.y, ca.z, ca.w, cb.x, cb.y, cb.z, cb.w};               \
            _Pragma("unroll")                                                             \
            for (int c = 0; c < CT; ++c)                                                  \
                _Pragma("unroll")                                                         \
                for (int j = 0; j < TXR; ++j)                                             \
                    acc[c][j] = fmaf(cv[j], F[c][j + 8 - kdx], acc[c][j]);                \
            ca = na; cb = nb;                                                             \
        }                                                                                 \
    }

    // kdy pairs: 16 feat loads issued together at the top of each iteration, then
    // two compute blocks. One ~600cy vmcnt wait per PAIR instead of per kdy; the
    // second row's loads complete under the first row's 288-FMA block. All arrays
    // are intra-iteration with static indices -> SROA-safe (no scratch).
    int kdy = klo;
    #pragma unroll 1
    for (; kdy + 1 <= khi; kdy += 2) {
        float fA[CT][16];
        float fB[CT][16];
        LOADF_K(fA, y + RR - kdy)
        LOADF_K(fB, y + RR - kdy - 1)
        COMPUTE_K(fA, kdy)
        COMPUTE_K(fB, kdy + 1)
    }
    if (kdy <= khi) {
        float fA[CT][16];
        LOADF_K(fA, y + RR - kdy)
        COMPUTE_K(fA, kdy)
    }
#undef LOADF_K
#undef COMPUTE_K

    float* ob = out + ((size_t)b * Cn + c0) * HWn + (size_t)y * Wn + x0;
    #pragma unroll
    for (int c = 0; c < CT; ++c) {
        *reinterpret_cast<float4*>(ob + (size_t)c * HWn)     = make_float4(acc[c][0], acc[c][1], acc[c][2], acc[c][3]);
        *reinterpret_cast<float4*>(ob + (size_t)c * HWn + 4) = make_float4(acc[c][4], acc[c][5], acc[c][6], acc[c][7]);
    }
}

extern "C" void kernel_launch(void* const* d_in, const int* in_sizes, int n_in,
                              void* d_out, int out_size, void* d_ws, size_t ws_size,
                              hipStream_t stream)
{
    const float* corr = (const float*)d_in[0];   // [16,81,96,96]
    const float* feat = (const float*)d_in[1];   // [16,256,96,96]
    float* out = (float*)d_out;                  // [16,256,96,96]

    const int grid = Bn * Hn * NCG;              // 16*96*4 = 6144
    corrT9_kernel<<<grid, NTH, 0, stream>>>(corr, feat, out);
}

// Round 10
// 249.471 us; speedup vs baseline: 2.6862x; 2.6862x over previous
//
#include <hip/hip_runtime.h>

// out[b,c,y,x] = sum_{kdy,kdx in [0,9)} corr[b, kdy*9+kdx, y+4-kdy, x+4-kdx] * feat[b,c, y+4-kdy, x+4-kdx]
// (zero padding outside [0,96) in both spatial dims)

#define RR 4
#define DD 9
#define D2 81
#define Bn 16
#define Cn 256
#define Hn 96
#define Wn 96
#define HWn (Hn*Wn)

#define NTX 12            // x-lane groups
#define TXR 8             // x outputs per thread
#define NTC 32            // channel lanes
#define CT  2             // channels per thread
#define NCB (NTC*CT)      // 64 channels per block
#define NCG (Cn/NCB)      // 4 channel groups
#define NTH (NTX*NTC)     // 384 threads
#define LW  100           // padded LDS row width: cols 0..3 zero pad, 4..99 data; 81*100*4 = 32400 B
#define LW4 (LW/4)        // 25 float4 per row

#define NXCD 8
#define PERX ((Bn*NCG*Hn)/NXCD)   // 768 blocks per XCD chunk

__global__ __launch_bounds__(NTH, 6)
void corrT10_kernel(const float* __restrict__ corr,
                    const float* __restrict__ feat,
                    float* __restrict__ out)
{
    __shared__ float lds[D2 * LW];          // 32400 B

    // Locality-ordered dispatch: XCD-chunked, y INNERMOST within a chunk.
    // Co-resident blocks on one XCD = consecutive y of the same (b,cg):
    // feat rows (9x reuse) and the corr row window stay in that XCD's L2.
    int bid   = blockIdx.x;
    int xcd   = bid & (NXCD - 1);
    int local = bid >> 3;                   // 0..767
    int L     = xcd * PERX + local;         // contiguous logical id per XCD
    int y     = L % Hn;                     // y innermost
    int t     = L / Hn;                     // 0..63
    int cg    = t & (NCG - 1);
    int b     = t >> 2;

    const int tid = threadIdx.x;
    const float* corrb = corr + (size_t)b * D2 * HWn;

    // ---- stage corr rows into LDS, x-shifted by kdx, zero-padded ----
    // lds[row][col] = corr[b, row, y+4-kdy, col - kdx]  (0 if OOB), row = kdy*9+kdx
    for (int idx = tid; idx < D2 * LW4; idx += NTH) {
        int row = idx / LW4;
        int c4  = idx - row * LW4;
        int kdy = row / DD;
        int kdx = row - kdy * DD;
        int sy  = y + RR - kdy;
        float4 v = make_float4(0.f, 0.f, 0.f, 0.f);
        if (sy >= 0 && sy < Hn) {
            const float* src = corrb + (size_t)row * HWn + sy * Wn;
            int col0 = c4 * 4;
            #pragma unroll
            for (int e = 0; e < 4; ++e) {
                int sx = col0 + e - kdx;
                if (sx >= 0 && sx < Wn) (&v.x)[e] = src[sx];
            }
        }
        *reinterpret_cast<float4*>(&lds[row * LW + c4 * 4]) = v;
    }
    __syncthreads();

    const int tx = tid % NTX;
    const int tc = tid / NTX;
    const int x0 = tx * TXR;
    const int c0 = cg * NCB + tc * CT;

    const float* featb = feat + ((size_t)b * Cn + c0) * HWn;

    float acc[CT][TXR] = {};

    // contiguous valid kdy range: sy = y+4-kdy in [0,96)
    const int klo = max(0, y - (Hn - 1 - RR));
    const int khi = min(DD - 1, y + RR);

    #pragma unroll 1
    for (int kdy = klo; kdy <= khi; ++kdy) {
        int sy = y + RR - kdy;

        // feat windows: f[c][t] = feat[c0+c, sy, x0-4+t], t in [0,16); OOB -> 0
        float f[CT][16];
        const float* frow = featb + sy * Wn + x0 - RR;
        #pragma unroll
        for (int c = 0; c < CT; ++c) {
            const float* p = frow + (size_t)c * HWn;
            float4 f0 = (tx == 0)       ? make_float4(0,0,0,0) : *reinterpret_cast<const float4*>(p);
            float4 f1 = *reinterpret_cast<const float4*>(p + 4);
            float4 f2 = *reinterpret_cast<const float4*>(p + 8);
            float4 f3 = (tx == NTX - 1) ? make_float4(0,0,0,0) : *reinterpret_cast<const float4*>(p + 12);
            f[c][0]=f0.x;  f[c][1]=f0.y;  f[c][2]=f0.z;  f[c][3]=f0.w;
            f[c][4]=f1.x;  f[c][5]=f1.y;  f[c][6]=f1.z;  f[c][7]=f1.w;
            f[c][8]=f2.x;  f[c][9]=f2.y;  f[c][10]=f2.z; f[c][11]=f2.w;
            f[c][12]=f3.x; f[c][13]=f3.y; f[c][14]=f3.z; f[c][15]=f3.w;
        }

        // cv for output x0+j lives at lds[row][x0+4+j] -> two aligned b128 per row.
        // Depth-1 prefetch of next kdx row's pair hides LDS latency under the FMA block.
        const float4* base = reinterpret_cast<const float4*>(lds) + (tx * 2 + 1) + kdy * DD * LW4;
        float4 ca = base[0];
        float4 cb = base[1];
        #pragma unroll
        for (int kdx = 0; kdx < DD; ++kdx) {
            float4 na = ca, nb = cb;
            if (kdx < DD - 1) {
                na = base[(kdx + 1) * LW4];
                nb = base[(kdx + 1) * LW4 + 1];
            }
            float cv[8] = {ca.x, ca.y, ca.z, ca.w, cb.x, cb.y, cb.z, cb.w};
            #pragma unroll
            for (int c = 0; c < CT; ++c)
                #pragma unroll
                for (int j = 0; j < TXR; ++j)
                    acc[c][j] = fmaf(cv[j], f[c][j + 8 - kdx], acc[c][j]);
            ca = na; cb = nb;
        }
    }

    float* ob = out + ((size_t)b * Cn + c0) * HWn + (size_t)y * Wn + x0;
    #pragma unroll
    for (int c = 0; c < CT; ++c) {
        *reinterpret_cast<float4*>(ob + (size_t)c * HWn)     = make_float4(acc[c][0], acc[c][1], acc[c][2], acc[c][3]);
        *reinterpret_cast<float4*>(ob + (size_t)c * HWn + 4) = make_float4(acc[c][4], acc[c][5], acc[c][6], acc[c][7]);
    }
}

extern "C" void kernel_launch(void* const* d_in, const int* in_sizes, int n_in,
                              void* d_out, int out_size, void* d_ws, size_t ws_size,
                              hipStream_t stream)
{
    const float* corr = (const float*)d_in[0];   // [16,81,96,96]
    const float* feat = (const float*)d_in[1];   // [16,256,96,96]
    float* out = (float*)d_out;                  // [16,256,96,96]

    const int grid = Bn * Hn * NCG;              // 16*96*4 = 6144
    corrT10_kernel<<<grid, NTH, 0, stream>>>(corr, feat, out);
}

// Round 11
// 190.525 us; speedup vs baseline: 3.5173x; 1.3094x over previous
//
#include <hip/hip_runtime.h>

// out[b,c,y,x] = sum_{kdy,kdx in [0,9)} corr[b, kdy*9+kdx, y+4-kdy, x+4-kdx] * feat[b,c, y+4-kdy, x+4-kdx]
// MFMA formulation: per (b,y):  out[C,X] = sum_kdy  A_kdy[C, K] * M_kdy[K, X]
//   A_kdy[c, sx_pad]  = feat[b, c, sy, sx_pad-4]        (bf16, zero-padded cols)
//   M_kdy[sx_pad, x]  = corr[b, kdy*9+(x+8-sx_pad), sy, sx_pad-4]   (banded: x <= sx_pad <= x+8)
// stored transposed in LDS as M_sh[x][sx_pad]; out-of-band entries zeroed once.
// Each 16-wide x-tile needs only sx_pad in [x0, x0+24] -> ONE K=32 MFMA per (c-tile, x-tile).

#define RR 4
#define DD 9
#define D2 81
#define Bn 16
#define Cn 256
#define Hn 96
#define Wn 96
#define HWn (Hn*Wn)
#define NTH 512
#define KW  104           // padded K width: sx_pad = sx+4, sx in [-4,100)

typedef __attribute__((ext_vector_type(8))) short bf16x8;
typedef __attribute__((ext_vector_type(4))) float f32x4;

__device__ __forceinline__ ushort f2bf(float f) {  // RNE fp32->bf16
    uint u = __float_as_uint(f);
    return (ushort)((u + 0x7FFFu + ((u >> 16) & 1u)) >> 16);
}

__global__ __launch_bounds__(NTH, 2)
void corrT11_kernel(const float* __restrict__ corr,
                    const float* __restrict__ feat,
                    float* __restrict__ out)
{
    __shared__ ushort A_sh[2][Cn][KW];   // 106496 B : feat rows, bf16, double-buffered
    __shared__ ushort M_sh[2][Wn][KW];   //  39936 B : banded weights^T, bf16, double-buffered

    // XCD-chunked: y contiguous per XCD (corr/feat row reuse in L2). grid 1536 = 8*192.
    int bid = blockIdx.x;
    int L   = (bid & 7) * 192 + (bid >> 3);
    int y   = L % Hn;
    int b   = L / Hn;

    const int tid  = threadIdx.x;
    const int lane = tid & 63;
    const int wid  = tid >> 6;            // 0..7 : wave id -> 32-channel strip
    const int mrow = lane & 15;           // M/N index within 16x16 tile
    const int kgrp = (lane >> 4) << 3;    // K sub-block base: 0,8,16,24

    // ---- zero both LDS buffers once (A pads + M out-of-band stay 0 forever) ----
    {
        uint* p = (uint*)A_sh;
        for (int t = tid; t < (int)(sizeof(A_sh) / 4); t += NTH) p[t] = 0u;
        uint* q = (uint*)M_sh;
        for (int t = tid; t < (int)(sizeof(M_sh) / 4); t += NTH) q[t] = 0u;
    }
    __syncthreads();

    const int klo = max(0, y - (Hn - 1 - RR));   // valid kdy: sy = y+4-kdy in [0,96)
    const int khi = min(DD - 1, y + RR);

    const int ac  = tid >> 1;            // A-staging: channel row (2 threads per row)
    const int seg = tid & 1;             // 48-float half-row
    const float* fbase = feat + (((size_t)b * Cn + ac) * Hn) * Wn + seg * 48;

    // ---- prologue: stage buffer 0 with kdy = klo ----
    {
        const int sy = y + RR - klo;
        const float* src = fbase + (size_t)sy * Wn;
        #pragma unroll
        for (int i = 0; i < 12; ++i) {
            float4 v = *reinterpret_cast<const float4*>(src + i * 4);
            uint lo = (uint)f2bf(v.x) | ((uint)f2bf(v.y) << 16);
            uint hi = (uint)f2bf(v.z) | ((uint)f2bf(v.w) << 16);
            *reinterpret_cast<uint2*>(&A_sh[0][ac][4 + seg * 48 + i * 4]) = make_uint2(lo, hi);
        }
        for (int t = tid; t < DD * Wn; t += NTH) {
            int kdx = t / Wn;
            int x   = t - kdx * Wn;
            int sx  = x + RR - kdx;
            int sxc = min(max(sx, 0), Wn - 1);   // OOB value multiplies zeroed A pad
            float v = corr[((size_t)b * D2 + klo * DD + kdx) * HWn + sy * Wn + sxc];
            M_sh[0][x][x + 2 * RR - kdx] = f2bf(v);
        }
    }

    f32x4 acc[2][6];
    #pragma unroll
    for (int ct = 0; ct < 2; ++ct)
        #pragma unroll
        for (int xt = 0; xt < 6; ++xt)
            acc[ct][xt] = (f32x4){0.f, 0.f, 0.f, 0.f};

    #pragma unroll 1
    for (int kk = klo; kk <= khi; ++kk) {
        const int pb = (kk - klo) & 1;
        __syncthreads();                          // buf[pb] staged & visible

        // -- issue next tile's global loads early; hold in regs across MFMA (T14 split) --
        const bool vn = (kk + 1 <= khi);          // block-uniform
        float4 fv[12];
        float  mv0 = 0.f, mv1 = 0.f;
        if (vn) {
            const int sy = y + RR - (kk + 1);
            const float* src = fbase + (size_t)sy * Wn;
            #pragma unroll
            for (int i = 0; i < 12; ++i)
                fv[i] = *reinterpret_cast<const float4*>(src + i * 4);
            {
                int t = tid;                      // t < 864 always (tid < 512)
                int kdx = t / Wn, x = t - kdx * Wn;
                int sx  = x + RR - kdx;
                int sxc = min(max(sx, 0), Wn - 1);
                mv0 = corr[((size_t)b * D2 + (kk + 1) * DD + kdx) * HWn + sy * Wn + sxc];
            }
            if (tid + NTH < DD * Wn) {
                int t = tid + NTH;
                int kdx = t / Wn, x = t - kdx * Wn;
                int sx  = x + RR - kdx;
                int sxc = min(max(sx, 0), Wn - 1);
                mv1 = corr[((size_t)b * D2 + (kk + 1) * DD + kdx) * HWn + sy * Wn + sxc];
            }
        }

        // -- MFMA phase: 12 x v_mfma_f32_16x16x32_bf16 per wave --
        #pragma unroll
        for (int xt = 0; xt < 6; ++xt) {
            const int kb = (xt == 5) ? 72 : xt * 16;   // K-window start (band coverage)
            bf16x8 bfr = *reinterpret_cast<const bf16x8*>(&M_sh[pb][xt * 16 + mrow][kb + kgrp]);
            #pragma unroll
            for (int ct = 0; ct < 2; ++ct) {
                bf16x8 afr = *reinterpret_cast<const bf16x8*>(&A_sh[pb][wid * 32 + ct * 16 + mrow][kb + kgrp]);
                acc[ct][xt] = __builtin_amdgcn_mfma_f32_16x16x32_bf16(afr, bfr, acc[ct][xt], 0, 0, 0);
            }
        }

        // -- write-phase: cvt + LDS writes into buf[pb^1] --
        if (vn) {
            #pragma unroll
            for (int i = 0; i < 12; ++i) {
                uint lo = (uint)f2bf(fv[i].x) | ((uint)f2bf(fv[i].y) << 16);
                uint hi = (uint)f2bf(fv[i].z) | ((uint)f2bf(fv[i].w) << 16);
                *reinterpret_cast<uint2*>(&A_sh[pb ^ 1][ac][4 + seg * 48 + i * 4]) = make_uint2(lo, hi);
            }
            {
                int t = tid;
                int kdx = t / Wn, x = t - kdx * Wn;
                M_sh[pb ^ 1][x][x + 2 * RR - kdx] = f2bf(mv0);
            }
            if (tid + NTH < DD * Wn) {
                int t = tid + NTH;
                int kdx = t / Wn, x = t - kdx * Wn;
                M_sh[pb ^ 1][x][x + 2 * RR - kdx] = f2bf(mv1);
            }
        }
    }

    // ---- epilogue: C/D layout col=lane&15, row=(lane>>4)*4+r  (m89-verified) ----
    const int csub = (lane >> 4) << 2;
    #pragma unroll
    for (int ct = 0; ct < 2; ++ct) {
        #pragma unroll
        for (int xt = 0; xt < 6; ++xt) {
            #pragma unroll
            for (int r = 0; r < 4; ++r) {
                int c = wid * 32 + ct * 16 + csub + r;
                int x = xt * 16 + mrow;
                out[(((size_t)b * Cn + c) * Hn + y) * Wn + x] = acc[ct][xt][r];
            }
        }
    }
}

extern "C" void kernel_launch(void* const* d_in, const int* in_sizes, int n_in,
                              void* d_out, int out_size, void* d_ws, size_t ws_size,
                              hipStream_t stream)
{
    const float* corr = (const float*)d_in[0];   // [16,81,96,96]
    const float* feat = (const float*)d_in[1];   // [16,256,96,96]
    float* out = (float*)d_out;                  // [16,256,96,96]

    const int grid = Bn * Hn;                    // 1536 blocks: one (b, y) each
    corrT11_kernel<<<grid, NTH, 0, stream>>>(corr, feat, out);
}